// Round 7
// baseline (71.505 us; speedup 1.0000x reference)
//
#include <hip/hip_runtime.h>

#define NSLICE 6
#define NPIX   4096
#define M      20
#define TPB    1024

// K(d)=exp(-(d/sigma)^2), sigma=0.1, on d in [-1,1]:
//   K(d) ~= c0 + sum_{m=1..M} 2*c_m*cos(pi*m*d), c_m=(sigma*sqrt(pi)/2)*exp(-(pi*m*sigma)^2/4)
#define C0         0.088622693f
#define TWO_C0     0.177245385f
#define AEXP_LOG2  0.035597112f    // (pi*sigma)^2/4 * log2(e)
#define DEN0       362.99854f      // C0 * NPIX

// ONE launch, ONE block per slice (6 x 1024), ZERO redundant moment work.
// Round-6 lesson: 8x-redundant moments (13.2us) > two-kernel chain (10.8us);
// per-node fixed cost ~4-5us, so single node + non-redundant compute wins.
// Phase 1: fg=tid&3 owns freqs 5fg+1..5fg+5 (Chebyshev from 2 trans starters),
// set=tid>>2 owns 16 pixels. 20 accumulators/thread -> ~50 VGPR, no spill.
__global__ __launch_bounds__(TPB) void bilateral_slice(
        const float* __restrict__ x, float* __restrict__ out) {
    __shared__ float4 part4[16][4][5];   // [wave][fg][freq] (Sc,Ss,Tc,Ts), 5 KB
    __shared__ float  xpart[16];
    __shared__ __align__(16) float fin[(M + 1) * 4];

    const int tid = threadIdx.x;
    const int s   = blockIdx.x;
    const float* xs = x + s * NPIX;

    const int fg  = tid & 3;
    const int set = tid >> 2;            // 256 sets x 16 px
    const float a = (float)(5 * fg);

    float Sc[5], Ss[5], Tc[5], Ts[5], X = 0.f;
    #pragma unroll
    for (int k = 0; k < 5; ++k) { Sc[k]=0.f; Ss[k]=0.f; Tc[k]=0.f; Ts[k]=0.f; }

    const float4* x4 = (const float4*)xs;
    #pragma unroll
    for (int j = 0; j < 4; ++j) {        // 16 px = 4 float4 (4-lane dup, L1 hit)
        float4 v4 = x4[set * 4 + j];
        float vv[4] = {v4.x, v4.y, v4.z, v4.w};
        #pragma unroll
        for (int u = 0; u < 4; ++u) {
            float v = vv[u];
            X += v;
            float h  = 0.5f * v;                             // revolutions
            float c1 = __builtin_amdgcn_cosf(h);             // cos(pi v)
            float tc = c1 + c1;
            float cp = __builtin_amdgcn_cosf(a * h);         // cos(pi a v)
            float sp = __builtin_amdgcn_sinf(a * h);
            float cc = __builtin_amdgcn_cosf(fmaf(a, h, h)); // cos(pi(a+1)v)
            float ss = __builtin_amdgcn_sinf(fmaf(a, h, h));
            #pragma unroll
            for (int k = 0; k < 5; ++k) {                    // freqs a+1..a+5
                Sc[k] += cc;  Ss[k] += ss;
                Tc[k] = fmaf(v, cc, Tc[k]);  Ts[k] = fmaf(v, ss, Ts[k]);
                float cn = fmaf(tc, cc, -cp);
                float sn = fmaf(tc, ss, -sp);
                cp = cc; cc = cn; sp = ss; ss = sn;
            }
        }
    }

    // Butterfly over sets within the wave (fg in low 2 bits is preserved).
    #pragma unroll
    for (int off = 4; off < 64; off <<= 1) {
        X += __shfl_xor(X, off);
        #pragma unroll
        for (int k = 0; k < 5; ++k) {
            Sc[k] += __shfl_xor(Sc[k], off);
            Ss[k] += __shfl_xor(Ss[k], off);
            Tc[k] += __shfl_xor(Tc[k], off);
            Ts[k] += __shfl_xor(Ts[k], off);
        }
    }
    const int lane = tid & 63;
    const int wv   = tid >> 6;                    // 16 waves
    if (lane < 4) {                               // lane == fg
        #pragma unroll
        for (int k = 0; k < 5; ++k)
            part4[wv][fg][k] = make_float4(Sc[k], Ss[k], Tc[k], Ts[k]);
        if (lane == 0) xpart[wv] = X;             // X counted once per wave
    }
    __syncthreads();

    // Cross-wave sums: 81 threads x 16 reads. Flat layout: [16][80] floats.
    if (tid < 81) {
        if (tid == 80) {
            float xx = 0.f;
            #pragma unroll
            for (int g = 0; g < 16; ++g) xx += xpart[g];
            fin[0] = DEN0;  fin[1] = C0 * xx;  fin[2] = 0.f;  fin[3] = 0.f;
        } else {
            const float* pf = (const float*)part4;
            float sum = 0.f;
            #pragma unroll
            for (int g = 0; g < 16; ++g) sum += pf[g * 80 + tid];
            int m = (tid >> 2) + 1;
            float fm = (float)m;
            float coef = TWO_C0 * __builtin_amdgcn_exp2f(-AEXP_LOG2 * fm * fm);
            fin[m * 4 + (tid & 3)] = coef * sum;
        }
    }
    __syncthreads();

    // Phase 2: recombine 4 consecutive pixels per thread (float4 in/out).
    const float4* F = (const float4*)fin;
    float4 vin = x4[tid];
    float vv[4] = {vin.x, vin.y, vin.z, vin.w};
    float rr[4];
    #pragma unroll
    for (int u = 0; u < 4; ++u) {
        float v  = vv[u];
        float h  = 0.5f * v;
        float s1 = __builtin_amdgcn_sinf(h);
        float c1 = __builtin_amdgcn_cosf(h);
        float4 f0 = F[0], f1 = F[1];
        float den = fmaf(c1, f1.x, f0.x);  den = fmaf(s1, f1.y, den);
        float num = fmaf(c1, f1.z, f0.y);  num = fmaf(s1, f1.w, num);
        float tc = c1 + c1, cm2 = 1.f, sm2 = 0.f, cm1 = c1, sm1 = s1;
        #pragma unroll
        for (int m = 2; m <= M; ++m) {
            float cn = fmaf(tc, cm1, -cm2);
            float sn = fmaf(tc, sm1, -sm2);
            cm2 = cm1; cm1 = cn; sm2 = sm1; sm1 = sn;
            float4 f = F[m];                       // LDS broadcast
            den = fmaf(cn, f.x, den);  den = fmaf(sn, f.y, den);
            num = fmaf(cn, f.z, num);  num = fmaf(sn, f.w, num);
        }
        rr[u] = num / den;
    }
    float4* o4 = (float4*)(out + s * NPIX);
    o4[tid] = make_float4(rr[0], rr[1], rr[2], rr[3]);
}

extern "C" void kernel_launch(void* const* d_in, const int* in_sizes, int n_in,
                              void* d_out, int out_size, void* d_ws, size_t ws_size,
                              hipStream_t stream) {
    const float* x = (const float*)d_in[0];
    float* out = (float*)d_out;
    bilateral_slice<<<dim3(NSLICE), dim3(TPB), 0, stream>>>(x, out);
}

// Round 8
// 59.800 us; speedup vs baseline: 1.1957x; 1.1957x over previous
//
#include <hip/hip_runtime.h>

#define NSLICE 6
#define NPIX   4096
#define M      20
#define TPB    512

// K(d)=exp(-(d/sigma)^2), sigma=0.1, on d in [-1,1]:
//   K(d) ~= c0 + sum_{m=1..M} 2*c_m*cos(pi*m*d), c_m=(sigma*sqrt(pi)/2)*exp(-(pi*m*sigma)^2/4)
#define C0         0.088622693f
#define TWO_C0     0.177245385f
#define AEXP_LOG2  0.035597112f    // (pi*sigma)^2/4 * log2(e)
#define DEN0       362.99854f      // C0 * NPIX

// Single launch, 48 blocks (8/slice), redundant full-slice moments per block
// (single graph node beats two-kernel chain when the kernel is trans-lean).
// Round-7 lesson: v_sin/v_cos issue at ~4 lanes/cyc/CU -> trans count is the
// kernel floor. 2-way fg split: fg0 = freqs 1..10 (2 trans/px, seeds free),
// fg1 = freqs 11..20 (4 trans/px, (c11,s11) by angle-addition). 24.6k
// lane-trans/CU vs round-6's 82k. 41 accums/thread -> ~60 VGPR, no spill.
__global__ __launch_bounds__(TPB) void bilateral_fused2(
        const float* __restrict__ x, float* __restrict__ out) {
    __shared__ float4 part4[8][2][10];   // [wave][fg][freq] (Sc,Ss,Tc,Ts), 2.5KB
    __shared__ float  xpart[8];
    __shared__ __align__(16) float fin[(M + 1) * 4];

    const int tid = threadIdx.x;
    const int s   = blockIdx.x >> 3;     // slice
    const int bt  = blockIdx.x & 7;      // phase-2 tile within slice
    const float* xs = x + s * NPIX;

    const int fg  = tid & 1;             // 0: freqs 1..10, 1: freqs 11..20
    const int set = tid >> 1;            // 256 sets x 16 px

    float Sc[10], Ss[10], Tc[10], Ts[10], X = 0.f;
    #pragma unroll
    for (int k = 0; k < 10; ++k) { Sc[k]=0.f; Ss[k]=0.f; Tc[k]=0.f; Ts[k]=0.f; }

    const float4* x4 = (const float4*)xs;
    #pragma unroll
    for (int j = 0; j < 4; ++j) {        // 16 px/thread (2-lane dup load, L1)
        float4 v4 = x4[set * 4 + j];
        float vv[4] = {v4.x, v4.y, v4.z, v4.w};
        #pragma unroll
        for (int u = 0; u < 4; ++u) {
            float v = vv[u];
            float h  = 0.5f * v;                      // revolutions for pi*v
            float c1 = __builtin_amdgcn_cosf(h);      // cos(pi v)
            float s1 = __builtin_amdgcn_sinf(h);      // sin(pi v)
            float tc = c1 + c1;
            float cp, sp, cc, ss;
            if (fg == 0) {
                X += v;                               // count once per pixel
                cp = 1.f;  sp = 0.f;                  // m=0 seed (free)
                cc = c1;   ss = s1;                   // m=1 seed
            } else {
                float cA = __builtin_amdgcn_cosf(10.f * h);   // cos(10 pi v)
                float sA = __builtin_amdgcn_sinf(10.f * h);
                cp = cA;  sp = sA;                    // m=10 seed
                cc = fmaf(cA, c1, -(sA * s1));        // cos(11 pi v)
                ss = fmaf(sA, c1,  (cA * s1));        // sin(11 pi v)
            }
            #pragma unroll
            for (int k = 0; k < 10; ++k) {            // freqs base+1..base+10
                Sc[k] += cc;  Ss[k] += ss;
                Tc[k] = fmaf(v, cc, Tc[k]);  Ts[k] = fmaf(v, ss, Ts[k]);
                float cn = fmaf(tc, cc, -cp);         // Chebyshev step
                float sn = fmaf(tc, ss, -sp);
                cp = cc; cc = cn; sp = ss; ss = sn;
            }
        }
    }

    // Butterfly over bits 1..5 (preserves fg in bit 0).
    #pragma unroll
    for (int off = 2; off < 64; off <<= 1) {
        X += __shfl_xor(X, off);
        #pragma unroll
        for (int k = 0; k < 10; ++k) {
            Sc[k] += __shfl_xor(Sc[k], off);
            Ss[k] += __shfl_xor(Ss[k], off);
            Tc[k] += __shfl_xor(Tc[k], off);
            Ts[k] += __shfl_xor(Ts[k], off);
        }
    }
    const int lane = tid & 63;
    const int wv   = tid >> 6;                        // 8 waves
    if (lane < 2) {                                   // lane == fg
        #pragma unroll
        for (int k = 0; k < 10; ++k)
            part4[wv][fg][k] = make_float4(Sc[k], Ss[k], Tc[k], Ts[k]);
        if (lane == 0) xpart[wv] = X;
    }
    __syncthreads();

    // Cross-wave sums. Flat identity: freq-major layout -> value (m0=tid>>2,
    // kind=tid&3) lives at float offset g*80 + tid of part4.
    if (tid < 81) {
        if (tid == 80) {
            float xx = 0.f;
            #pragma unroll
            for (int g = 0; g < 8; ++g) xx += xpart[g];
            fin[0] = DEN0;  fin[1] = C0 * xx;  fin[2] = 0.f;  fin[3] = 0.f;
        } else {
            const float* pf = (const float*)part4;
            float sum = 0.f;
            #pragma unroll
            for (int g = 0; g < 8; ++g) sum += pf[g * 80 + tid];
            int m = (tid >> 2) + 1;
            float fm = (float)m;
            float coef = TWO_C0 * __builtin_amdgcn_exp2f(-AEXP_LOG2 * fm * fm);
            fin[m * 4 + (tid & 3)] = coef * sum;
        }
    }
    __syncthreads();

    // ---- Phase 2: this block's 512-pixel tile, 1 px/thread.
    const int p = bt * TPB + tid;
    float v  = xs[p];
    float h  = 0.5f * v;
    float s1 = __builtin_amdgcn_sinf(h);
    float c1 = __builtin_amdgcn_cosf(h);
    const float4* F = (const float4*)fin;
    float4 f0 = F[0], f1 = F[1];
    float den = fmaf(c1, f1.x, f0.x);  den = fmaf(s1, f1.y, den);
    float num = fmaf(c1, f1.z, f0.y);  num = fmaf(s1, f1.w, num);
    float tc = c1 + c1, cm2 = 1.f, sm2 = 0.f, cm1 = c1, sm1 = s1;
    #pragma unroll
    for (int m = 2; m <= M; ++m) {
        float cn = fmaf(tc, cm1, -cm2);
        float sn = fmaf(tc, sm1, -sm2);
        cm2 = cm1; cm1 = cn; sm2 = sm1; sm1 = sn;
        float4 f = F[m];                              // LDS broadcast
        den = fmaf(cn, f.x, den);  den = fmaf(sn, f.y, den);
        num = fmaf(cn, f.z, num);  num = fmaf(sn, f.w, num);
    }
    out[s * NPIX + p] = num / den;
}

extern "C" void kernel_launch(void* const* d_in, const int* in_sizes, int n_in,
                              void* d_out, int out_size, void* d_ws, size_t ws_size,
                              hipStream_t stream) {
    const float* x = (const float*)d_in[0];
    float* out = (float*)d_out;
    bilateral_fused2<<<dim3(NSLICE * 8), dim3(TPB), 0, stream>>>(x, out);
}

// Round 9
// 54.722 us; speedup vs baseline: 1.3067x; 1.0928x over previous
//
#include <hip/hip_runtime.h>

#define NSLICE 6
#define NPIX   4096
#define M      20             // Fourier frequencies 1..M

// K(d) = exp(-(d/sigma)^2), sigma=0.1, on d in [-1,1]:
//   K(d) ~= c0 + sum_{m=1..M} 2*c_m*cos(pi*m*d),
//   c_m = (sigma*sqrt(pi)/2)*exp(-(pi*m*sigma)^2/4)
// Tail at M=20 ~5e-6 abs; periodization ~exp(-100).
#define C0         0.088622693f    // sigma*sqrt(pi)/2
#define TWO_C0     0.177245385f
#define AEXP_LOG2  0.035597112f    // (pi*sigma)^2/4 * log2(e)
#define DEN0       362.99854f      // C0 * NPIX

// Measured-best structure (round 5, 54.5 us total): two kernels, ZERO
// redundant moment work. Rounds 6-8 showed single-node variants lose:
// redundant per-block moments cost ~8-10 us compute vs the ~4.3 us node
// they save. Total is 73% harness fixed cost (256 MiB ws-poison fill at
// 84% HBM peak) — that part is at ITS roofline.
//
// K1: one block per (frequency m, slice). 256 threads x 16 px. Only 5 live
// accumulators/thread -> no spill (round-4 pathology). sin(pi*m*v) via raw
// v_sin_f32 in revolutions (0.5*m*v) — no OCML call, no recurrence.
// ws layout: ws[(s*(M+1) + m)*4 + {0:Sc,1:Ss,2:Tc,3:Ts}], m=0 slot = consts.
__global__ __launch_bounds__(256) void moments_kernel(
        const float* __restrict__ x, float* __restrict__ ws) {
    const int mi = blockIdx.x;           // 0..19 -> frequency mi+1
    const int s  = blockIdx.y;
    const float fm = (float)(mi + 1);
    const int tid = threadIdx.x;
    const float4* x4 = (const float4*)(x + s * NPIX);

    float Sc = 0.f, Ss = 0.f, Tc = 0.f, Ts = 0.f, X = 0.f;
    #pragma unroll
    for (int j = 0; j < NPIX / 4 / 256; ++j) {       // 4 iters, coalesced 16B
        float4 v4 = x4[j * 256 + tid];
        float vv[4] = {v4.x, v4.y, v4.z, v4.w};
        #pragma unroll
        for (int k = 0; k < 4; ++k) {
            float v   = vv[k];
            float arg = 0.5f * fm * v;               // revolutions
            float sn  = __builtin_amdgcn_sinf(arg);  // v_sin_f32
            float cn  = __builtin_amdgcn_cosf(arg);  // v_cos_f32
            Sc += cn;  Ss += sn;
            Tc = fmaf(v, cn, Tc);
            Ts = fmaf(v, sn, Ts);
            X += v;
        }
    }

    #pragma unroll
    for (int off = 1; off < 64; off <<= 1) {
        Sc += __shfl_xor(Sc, off);  Ss += __shfl_xor(Ss, off);
        Tc += __shfl_xor(Tc, off);  Ts += __shfl_xor(Ts, off);
        X  += __shfl_xor(X,  off);
    }
    __shared__ float red[4][5];
    const int w = tid >> 6;
    if ((tid & 63) == 0) {
        red[w][0] = Sc; red[w][1] = Ss; red[w][2] = Tc; red[w][3] = Ts; red[w][4] = X;
    }
    __syncthreads();
    if (tid == 0) {
        float sc = 0.f, ss = 0.f, tc = 0.f, ts = 0.f, xx = 0.f;
        #pragma unroll
        for (int ww = 0; ww < 4; ++ww) {
            sc += red[ww][0]; ss += red[ww][1]; tc += red[ww][2];
            ts += red[ww][3]; xx += red[ww][4];
        }
        float coef = TWO_C0 * __builtin_amdgcn_exp2f(-AEXP_LOG2 * fm * fm);
        float* f = ws + (s * (M + 1) + (mi + 1)) * 4;
        f[0] = coef * sc;  f[1] = coef * ss;
        f[2] = coef * tc;  f[3] = coef * ts;
        if (mi == 0) {                    // constant terms, written once/slice
            float* f0 = ws + s * (M + 1) * 4;
            f0[0] = DEN0;  f0[1] = C0 * xx;  f0[2] = 0.f;  f0[3] = 0.f;
        }
    }
}

// K2: one pixel per thread, 48 blocks x 512. F table staged in LDS and read
// per recurrence step (same-address broadcast, conflict-free). ~25 live VGPRs.
__global__ __launch_bounds__(512) void recombine_kernel(
        const float* __restrict__ x, const float* __restrict__ ws,
        float* __restrict__ out) {
    const int s = blockIdx.y;
    const int p = blockIdx.x * 512 + threadIdx.x;
    __shared__ __align__(16) float fin[(M + 1) * 4];
    if (threadIdx.x < (M + 1) * 4)
        fin[threadIdx.x] = ws[s * (M + 1) * 4 + threadIdx.x];
    __syncthreads();

    const float v  = x[s * NPIX + p];
    const float s1 = __builtin_amdgcn_sinf(0.5f * v);   // sin(pi*v)
    const float c1 = __builtin_amdgcn_cosf(0.5f * v);   // cos(pi*v)
    const float4* F = (const float4*)fin;

    float4 f0 = F[0], f1 = F[1];
    float den = f0.x, num = f0.y;
    den = fmaf(c1, f1.x, den);  den = fmaf(s1, f1.y, den);
    num = fmaf(c1, f1.z, num);  num = fmaf(s1, f1.w, num);

    const float tc = c1 + c1;
    float cm2 = 1.f, sm2 = 0.f, cm1 = c1, sm1 = s1;
    #pragma unroll
    for (int m = 2; m <= M; ++m) {        // Chebyshev recurrence in xp only
        float cn = fmaf(tc, cm1, -cm2);
        float sn = fmaf(tc, sm1, -sm2);
        cm2 = cm1; cm1 = cn; sm2 = sm1; sm1 = sn;
        float4 f = F[m];                  // ds_read_b128 broadcast
        den = fmaf(cn, f.x, den);  den = fmaf(sn, f.y, den);
        num = fmaf(cn, f.z, num);  num = fmaf(sn, f.w, num);
    }
    out[s * NPIX + p] = num / den;
}

extern "C" void kernel_launch(void* const* d_in, const int* in_sizes, int n_in,
                              void* d_out, int out_size, void* d_ws, size_t ws_size,
                              hipStream_t stream) {
    const float* x = (const float*)d_in[0];
    float* out = (float*)d_out;
    float* ws  = (float*)d_ws;            // 6*21*4 floats = 2016 B used
    moments_kernel<<<dim3(M, NSLICE), dim3(256), 0, stream>>>(x, ws);
    recombine_kernel<<<dim3(NPIX / 512, NSLICE), dim3(512), 0, stream>>>(x, ws, out);
}